// Round 4
// baseline (898.017 us; speedup 1.0000x reference)
//
#include <hip/hip_runtime.h>
#include <hip/hip_fp16.h>
#include <math.h>

#define NN 100000
#define NE 1600000
#define NB ((NN + 255) >> 8)   // 391 buckets of 256 nodes
#define CHUNK 8192
#define CAP 8192

typedef __attribute__((ext_vector_type(4))) float floatx4;
typedef __attribute__((ext_vector_type(8))) short shortx8;

// ---------------- bucketed CSR build ----------------

__global__ __launch_bounds__(256)
void coarse_hist(const int* __restrict__ ei, int* __restrict__ bucket_cnt, int E) {
    __shared__ int h[512];
    int t = threadIdx.x;
    for (int i = t; i < 512; i += 256) h[i] = 0;
    __syncthreads();
    int base = blockIdx.x * CHUNK;
    int lim = min(base + CHUNK, E);
    for (int e = base + t; e < lim; e += 256) {
        int d = ei[E + e];
        atomicAdd(&h[d >> 8], 1);
    }
    __syncthreads();
    for (int i = t; i < 512; i += 256)
        if (h[i]) atomicAdd(&bucket_cnt[i], h[i]);
}

__global__ void scan_buckets(const int* __restrict__ bucket_cnt,
                             int* __restrict__ bucket_base,
                             int* __restrict__ bucket_fill) {
    __shared__ int sh[512];
    int t = threadIdx.x;  // 512 threads
    int v = (t < NB) ? bucket_cnt[t] : 0;
    sh[t] = v;
    __syncthreads();
    for (int off = 1; off < 512; off <<= 1) {
        int u = (t >= off) ? sh[t - off] : 0;
        __syncthreads();
        sh[t] += u;
        __syncthreads();
    }
    int ex = (t == 0) ? 0 : sh[t - 1];
    if (t <= NB) bucket_base[t] = ex;
    if (t < NB) bucket_fill[t] = ex;
}

__global__ __launch_bounds__(256)
void coarse_scatter(const int* __restrict__ ei, int* __restrict__ bucket_fill,
                    unsigned long long* __restrict__ pairs, int E) {
    __shared__ int h[512];
    __shared__ int base[512];
    int t = threadIdx.x;
    for (int i = t; i < 512; i += 256) h[i] = 0;
    __syncthreads();
    int cbase = blockIdx.x * CHUNK;
    int lim = min(cbase + CHUNK, E);
    for (int e = cbase + t; e < lim; e += 256) {
        int d = ei[E + e];
        atomicAdd(&h[d >> 8], 1);
    }
    __syncthreads();
    for (int i = t; i < 512; i += 256)
        base[i] = h[i] ? atomicAdd(&bucket_fill[i], h[i]) : 0;
    __syncthreads();
    for (int i = t; i < 512; i += 256) h[i] = 0;
    __syncthreads();
    for (int e = cbase + t; e < lim; e += 256) {
        int s = ei[e];
        int d = ei[E + e];
        int b = d >> 8;
        int r = atomicAdd(&h[b], 1);
        pairs[base[b] + r] =
            ((unsigned long long)(unsigned)d << 32) | (unsigned)s;
    }
}

__global__ __launch_bounds__(256)
void fine_csr(const unsigned long long* __restrict__ pairs,
              const int* __restrict__ bucket_base,
              int* __restrict__ rowptr, int* __restrict__ colid,
              float* __restrict__ dinv, int n) {
    __shared__ int hist[256];
    __shared__ int offs[256];
    __shared__ int rank[256];
    __shared__ int lbuf[CAP];
    int b = blockIdx.x, t = threadIdx.x;
    int beg = bucket_base[b], end = bucket_base[b + 1];
    int cnt = end - beg;
    hist[t] = 0; rank[t] = 0;
    __syncthreads();
    for (int i = t; i < cnt; i += 256) {
        int d = (int)(pairs[beg + i] >> 32);
        atomicAdd(&hist[d & 255], 1);
    }
    __syncthreads();
    int v = hist[t];
    offs[t] = v;
    __syncthreads();
    for (int off = 1; off < 256; off <<= 1) {
        int u = (t >= off) ? offs[t - off] : 0;
        __syncthreads();
        offs[t] += u;
        __syncthreads();
    }
    int ex = (t == 0) ? 0 : offs[t - 1];
    int node = (b << 8) + t;
    if (node < n) {
        rowptr[node] = beg + ex;
        dinv[node] = rsqrtf((float)v + 1.0f);
    } else if (node == n) {
        rowptr[n] = beg + ex;
    }
    __syncthreads();
    offs[t] = ex;
    __syncthreads();
    for (int i = t; i < cnt; i += 256) {
        unsigned long long p = pairs[beg + i];
        int d = (int)(p >> 32) & 255;
        int s = (int)(p & 0xffffffffu);
        int r = atomicAdd(&rank[d], 1);
        lbuf[offs[d] + r] = s;
    }
    __syncthreads();
    for (int i = t; i < cnt; i += 256) colid[beg + i] = lbuf[i];
}

// ---------------- weight prep: W[K][OUT] fp32 -> swizzled bf16 hi/lo fragments ----
// all 6 layers in ONE launch (segment dispatch on flat index).

__device__ __forceinline__ void wsplit_one(const float* __restrict__ W,
                                           unsigned short* __restrict__ Wsw,
                                           int i, int K, int OUT) {
    int k = i / OUT, o = i % OUT;
    float w = W[i];
    unsigned u = __float_as_uint(w);
    float r = w - __uint_as_float(u & 0xFFFF0000u);
    int NT = OUT >> 4;
    int ktc = k >> 5, q = (k >> 3) & 3, j = k & 7;
    int nt = o >> 4, mm = o & 15;
    int lane = (q << 4) | mm;
    size_t base = ((((size_t)(ktc * NT + nt) * 2) * 64 + lane) << 3) + j;
    Wsw[base] = (unsigned short)(u >> 16);
    Wsw[base + 512] = (unsigned short)(__float_as_uint(r) >> 16);  // h=1: +64*8
}

__global__ __launch_bounds__(256)
void wsplit_all(const float* __restrict__ W0, unsigned short* __restrict__ O0,
                const float* __restrict__ W1, unsigned short* __restrict__ O1,
                const float* __restrict__ W2, unsigned short* __restrict__ O2,
                const float* __restrict__ W3, unsigned short* __restrict__ O3,
                const float* __restrict__ W4, unsigned short* __restrict__ O4,
                const float* __restrict__ W5, unsigned short* __restrict__ O5) {
    int i = blockIdx.x * 256 + threadIdx.x;
    // sizes: e1 20480, e2 16384, e3 8192, d1 12288, d2 16384, d3 16384
    if (i < 20480) { wsplit_one(W0, O0, i, 160, 128); return; }
    i -= 20480;
    if (i < 16384) { wsplit_one(W1, O1, i, 128, 128); return; }
    i -= 16384;
    if (i < 8192)  { wsplit_one(W2, O2, i, 128, 64);  return; }
    i -= 8192;
    if (i < 12288) { wsplit_one(W3, O3, i, 96, 128);  return; }
    i -= 12288;
    if (i < 16384) { wsplit_one(W4, O4, i, 128, 128); return; }
    i -= 16384;
    if (i < 16384) { wsplit_one(W5, O5, i, 128, 128); }
}

// ---------------- MFMA GEMM ----------------
// Y16 CHUNK-MAJOR: Y[(nt*n + row)*16 + m] fp16, chunk nt = 16 features
// (32 B per (node,chunk) unit -> prop gathers hit one 3.2 MB XCD-L2-resident slice).
// Two input pointers: columns [0,K1) from X1 (stride K1), [K1,K) from X2 (stride K-K1).

__device__ __forceinline__ void split8(const float* v, shortx8& hi, shortx8& lo) {
#pragma unroll
    for (int i = 0; i < 8; i++) {
        unsigned u = __float_as_uint(v[i]);
        float r = v[i] - __uint_as_float(u & 0xFFFF0000u);
        hi[i] = (short)(u >> 16);
        lo[i] = (short)(__float_as_uint(r) >> 16);
    }
}

template <int OUT, int K, int K1>
__global__ __launch_bounds__(512)
void gemm_mfma(const float* __restrict__ X1, const float* __restrict__ X2,
               const unsigned short* __restrict__ Wsw,
               const float* __restrict__ dinv,
               __half* __restrict__ Y, int ntiles) {
    constexpr int NT = OUT / 16;
    constexpr int NKTC = K / 32;
    constexpr int K2 = K - K1;
    constexpr int PERC = OUT * 128;  // bytes per ktc chunk
    constexpr int CSZ = (65536 / PERC < NKTC) ? (65536 / PERC) : NKTC;
    __shared__ __align__(16) unsigned short lds[CSZ * PERC / 2];

    const int t = threadIdx.x;
    const int wave = t >> 6, lane = t & 63;
    const int m = lane & 15, q = lane >> 4;
    const int tile = blockIdx.x * 8 + wave;
    const bool act = tile < ntiles;
    const int row = act ? tile * 16 + m : 0;
    const int nfull = ntiles * 16;
    const float* ap1 = X1 + (size_t)row * K1 + q * 8;
    const float* ap2 = (K2 > 0) ? (X2 + (size_t)row * K2 + q * 8) : X1;

    floatx4 acc[NT];
#pragma unroll
    for (int nt = 0; nt < NT; nt++) acc[nt] = (floatx4){0.f, 0.f, 0.f, 0.f};

#pragma unroll
    for (int c0 = 0; c0 < NKTC; c0 += CSZ) {
        const int cl = (NKTC - c0 < CSZ) ? (NKTC - c0) : CSZ;
        if (c0 != 0) __syncthreads();
        {
            const float4* gs = (const float4*)Wsw + (size_t)c0 * (PERC / 16);
            float4* ld = (float4*)lds;
            int tot = cl * (PERC / 16);
            for (int i = t; i < tot; i += 512) ld[i] = gs[i];
        }
        __syncthreads();
        if (act) {
#pragma unroll
            for (int ktc = 0; ktc < cl; ktc++) {
                const int kg = (c0 + ktc) * 32;
                const float* p = (kg < K1) ? (ap1 + kg) : (ap2 + (kg - K1));
                float av[8];
                *(float4*)&av[0] = *(const float4*)(p);
                *(float4*)&av[4] = *(const float4*)(p + 4);
                shortx8 ahi, alo;
                split8(av, ahi, alo);
#pragma unroll
                for (int nt = 0; nt < NT; nt++) {
                    const unsigned short* fb =
                        lds + ((((ktc * NT + nt) * 2) * 64 + lane) << 3);
                    shortx8 bhi = *(const shortx8*)fb;
                    shortx8 blo = *(const shortx8*)(fb + 512);
                    acc[nt] = __builtin_amdgcn_mfma_f32_16x16x32_bf16(ahi, bhi, acc[nt], 0, 0, 0);
                    acc[nt] = __builtin_amdgcn_mfma_f32_16x16x32_bf16(ahi, blo, acc[nt], 0, 0, 0);
                    acc[nt] = __builtin_amdgcn_mfma_f32_16x16x32_bf16(alo, bhi, acc[nt], 0, 0, 0);
                }
            }
        }
    }

    if (act) {
        float di[4];
#pragma unroll
        for (int r = 0; r < 4; r++) di[r] = dinv[tile * 16 + q * 4 + r];
#pragma unroll
        for (int nt = 0; nt < NT; nt++) {
#pragma unroll
            for (int r = 0; r < 4; r++) {
                int orow = tile * 16 + q * 4 + r;
                Y[((size_t)nt * nfull + orow) * 16 + m] =
                    __float2half_rn(acc[nt][r] * di[r]);
            }
        }
    }
}

// ---------------- chunked propagation v3: LDS-staged colid, slot-per-node ----------------
// Block = 32 nodes x 1 chunk (16 features), 4 waves. chunk = bid % NCH -> XCD
// round-robin pins each 3.2 MB chunk slice to one XCD's L2 (round-1 verified:
// FETCH 192 -> 43 MB). Fixes vs rounds 1/2:
//  - colid slice staged to LDS via coalesced nontemporal loads: the scattered
//    inner loop reads indices from LDS (no HBM-latency colid chain, no L2
//    pollution of the pinned chunk).
//  - 100K waves/prop (same as row-major kernel), rowptr staged per block.
//  - slot-per-node private accumulation: no cross-lane reduce.

template <int NCH, bool TANH>
__global__ __launch_bounds__(256, 8)
void prop_chunk2(const __half2* __restrict__ hs, const float* __restrict__ dinv,
                 const int* __restrict__ rowptr, const int* __restrict__ colid,
                 const float* __restrict__ bias, float* __restrict__ out,
                 int ldo, int n) {
    constexpr int LCAP = 3072;           // 12 KB; block edge-count ~Poisson(512)
    __shared__ int lcol[LCAP];
    __shared__ int srow[33];
    int bid = blockIdx.x;
    int c = bid & (NCH - 1);
    int nb = bid / NCH;
    int t = threadIdx.x;
    int n0 = nb * 32;                    // n % 32 == 0
    if (t < 33) srow[t] = rowptr[n0 + t];
    __syncthreads();
    int blockBeg = srow[0], blockEnd = srow[32];
    int cnt = blockEnd - blockBeg;
    bool inLds = (cnt <= LCAP);
    if (inLds) {
        for (int i = t; i < cnt; i += 256)
            lcol[i] = __builtin_nontemporal_load(colid + blockBeg + i);
    }
    __syncthreads();

    int wave = t >> 6, lane = t & 63;
    int slot = lane >> 3, f = lane & 7;
    int li = wave * 8 + slot;            // local node 0..31
    int node = n0 + li;
    const __half2* __restrict__ base = hs + (size_t)c * (size_t)n * 8;
    int beg = srow[li] - blockBeg, end = srow[li + 1] - blockBeg;

    auto body = [&](auto getc) {
        float ax = 0.f, ay = 0.f, bx = 0.f, by = 0.f;
        int e = beg;
        for (; e + 8 <= end; e += 8) {
            int s0 = getc(e),     s1 = getc(e + 1);
            int s2 = getc(e + 2), s3 = getc(e + 3);
            int s4 = getc(e + 4), s5 = getc(e + 5);
            int s6 = getc(e + 6), s7 = getc(e + 7);
            __half2 v0 = base[(unsigned)(s0 * 8 + f)];
            __half2 v1 = base[(unsigned)(s1 * 8 + f)];
            __half2 v2 = base[(unsigned)(s2 * 8 + f)];
            __half2 v3 = base[(unsigned)(s3 * 8 + f)];
            __half2 v4 = base[(unsigned)(s4 * 8 + f)];
            __half2 v5 = base[(unsigned)(s5 * 8 + f)];
            __half2 v6 = base[(unsigned)(s6 * 8 + f)];
            __half2 v7 = base[(unsigned)(s7 * 8 + f)];
            float2 f0 = __half22float2(v0), f1 = __half22float2(v1);
            float2 f2 = __half22float2(v2), f3 = __half22float2(v3);
            float2 f4 = __half22float2(v4), f5 = __half22float2(v5);
            float2 f6 = __half22float2(v6), f7 = __half22float2(v7);
            ax += f0.x + f2.x + f4.x + f6.x;
            ay += f0.y + f2.y + f4.y + f6.y;
            bx += f1.x + f3.x + f5.x + f7.x;
            by += f1.y + f3.y + f5.y + f7.y;
        }
        if (e + 4 <= end) {
            int s0 = getc(e), s1 = getc(e + 1), s2 = getc(e + 2), s3 = getc(e + 3);
            __half2 v0 = base[(unsigned)(s0 * 8 + f)];
            __half2 v1 = base[(unsigned)(s1 * 8 + f)];
            __half2 v2 = base[(unsigned)(s2 * 8 + f)];
            __half2 v3 = base[(unsigned)(s3 * 8 + f)];
            float2 f0 = __half22float2(v0), f1 = __half22float2(v1);
            float2 f2 = __half22float2(v2), f3 = __half22float2(v3);
            ax += f0.x + f2.x; ay += f0.y + f2.y;
            bx += f1.x + f3.x; by += f1.y + f3.y;
            e += 4;
        }
        for (; e < end; e++) {
            int s = getc(e);
            float2 v = __half22float2(base[(unsigned)(s * 8 + f)]);
            ax += v.x; ay += v.y;
        }
        float2 sv = __half22float2(base[(size_t)node * 8 + f]);
        float di = dinv[node];
        float2 bb = *(const float2*)(bias + c * 16 + 2 * f);
        float ox = di * (ax + bx + sv.x) + bb.x;
        float oy = di * (ay + by + sv.y) + bb.y;
        if (TANH) { ox = tanhf(ox); oy = tanhf(oy); }
        *(float2*)(out + (size_t)node * ldo + c * 16 + 2 * f) = make_float2(ox, oy);
    };
    if (inLds) body([&](int i) { return lcol[i]; });
    else       body([&](int i) { return colid[blockBeg + i]; });
}

// ---------------- launch ----------------

extern "C" void kernel_launch(void* const* d_in, const int* in_sizes, int n_in,
                              void* d_out, int out_size, void* d_ws, size_t ws_size,
                              hipStream_t stream) {
    const int n = NN, E = NE;
    const float* feature   = (const float*)d_in[0];
    const float* condition = (const float*)d_in[1];
    const int*   ei        = (const int*)d_in[2];
    const float* W_e1 = (const float*)d_in[3];  const float* b_e1 = (const float*)d_in[4];
    const float* W_e2 = (const float*)d_in[5];  const float* b_e2 = (const float*)d_in[6];
    const float* W_e3 = (const float*)d_in[7];  const float* b_e3 = (const float*)d_in[8];
    const float* W_d1 = (const float*)d_in[9];  const float* b_d1 = (const float*)d_in[10];
    const float* W_d2 = (const float*)d_in[11]; const float* b_d2 = (const float*)d_in[12];
    const float* W_d3 = (const float*)d_in[13]; const float* b_d3 = (const float*)d_in[14];
    float* out = (float*)d_out;

    float*  A    = (float*)d_ws;                    // n*160 floats
    __half* H16  = (__half*)(A + (size_t)n * 160);  // n*128 halves
    float*  dinv = (float*)(H16 + (size_t)n * 128); // n
    int* rowptr  = (int*)(dinv + n);                // n+1
    int* colid   = rowptr + n + 1;                  // E
    uintptr_t pp = (uintptr_t)(colid + E);
    pp = (pp + 15) & ~(uintptr_t)15;
    unsigned long long* pairs = (unsigned long long*)pp;  // E
    int* bucket_cnt  = (int*)(pairs + E);           // 512
    int* bucket_base = bucket_cnt + 512;            // 512
    int* bucket_fill = bucket_base + 512;           // 512
    uintptr_t wp = (uintptr_t)(bucket_fill + 512);
    wp = (wp + 15) & ~(uintptr_t)15;
    unsigned short* wt = (unsigned short*)wp;
    unsigned short* e1w = wt;              unsigned short* e2w = e1w + 160 * 128 * 2;
    unsigned short* e3w = e2w + 128*128*2; unsigned short* d1w = e3w + 128 * 64 * 2;
    unsigned short* d2w = d1w + 96*128*2;  unsigned short* d3w = d2w + 128 * 128 * 2;

    hipMemsetAsync(bucket_cnt, 0, 512 * sizeof(int), stream);

    int nbc = (E + CHUNK - 1) / CHUNK;
    coarse_hist<<<nbc, 256, 0, stream>>>(ei, bucket_cnt, E);
    scan_buckets<<<1, 512, 0, stream>>>(bucket_cnt, bucket_base, bucket_fill);
    coarse_scatter<<<nbc, 256, 0, stream>>>(ei, bucket_fill, pairs, E);
    fine_csr<<<NB, 256, 0, stream>>>(pairs, bucket_base, rowptr, colid, dinv, n);

    wsplit_all<<<(90112 + 255) / 256, 256, 0, stream>>>(
        W_e1, e1w, W_e2, e2w, W_e3, e3w, W_d1, d1w, W_d2, d2w, W_d3, d3w);

    const int ntiles = n / 16;          // 6250 exactly
    const int gb = (ntiles + 7) / 8;    // 8 waves per block
    const int pblk = n / 32;            // 3125 node-blocks (32 nodes/block)

    // encoder (e1 reads feature+condition directly; no concat)
    gemm_mfma<128, 160, 128><<<gb, 512, 0, stream>>>(feature, condition, e1w, dinv, H16, ntiles);
    prop_chunk2<8, true><<<8 * pblk, 256, 0, stream>>>((const __half2*)H16, dinv, rowptr, colid, b_e1, A, 128, n);
    gemm_mfma<128, 128, 128><<<gb, 512, 0, stream>>>(A, nullptr, e2w, dinv, H16, ntiles);
    prop_chunk2<8, true><<<8 * pblk, 256, 0, stream>>>((const __half2*)H16, dinv, rowptr, colid, b_e2, A, 128, n);
    gemm_mfma<64, 128, 128><<<gb, 512, 0, stream>>>(A, nullptr, e3w, dinv, H16, ntiles);
    prop_chunk2<4, false><<<4 * pblk, 256, 0, stream>>>((const __half2*)H16, dinv, rowptr, colid, b_e3, A, 64, n);

    // decoder (d1 reads z (ld=64) + condition directly; no condcopy)
    gemm_mfma<128, 96, 64><<<gb, 512, 0, stream>>>(A, condition, d1w, dinv, H16, ntiles);
    prop_chunk2<8, true><<<8 * pblk, 256, 0, stream>>>((const __half2*)H16, dinv, rowptr, colid, b_d1, A, 128, n);
    gemm_mfma<128, 128, 128><<<gb, 512, 0, stream>>>(A, nullptr, d2w, dinv, H16, ntiles);
    prop_chunk2<8, true><<<8 * pblk, 256, 0, stream>>>((const __half2*)H16, dinv, rowptr, colid, b_d2, A, 128, n);
    gemm_mfma<128, 128, 128><<<gb, 512, 0, stream>>>(A, nullptr, d3w, dinv, H16, ntiles);
    prop_chunk2<8, false><<<8 * pblk, 256, 0, stream>>>((const __half2*)H16, dinv, rowptr, colid, b_d3, out, 128, n);
}